// Round 14
// baseline (88.762 us; speedup 1.0000x reference)
//
#include <hip/hip_runtime.h>

// MultiGaussSpatialConv: B=1, N=M=8192, D=3, C=16, fp32.
// out[n,c] = sum_i w_i * (sum_m e_i(n,m) yf[m,c]) / (sum_m e_i(n,m))
// e_i = exp(-d2/(2 s^2)), 1/(2 s^2) = {200, 50, 12.5} -> e0 = e2^16, e1 = e2^4.
//
// R14: (a) native v_pk_fma_f32 via __builtin_elementwise_fma on float2
// ext-vectors (R13's inline asm likely forced v_mov marshaling -> its -30%
// static cut was 0% dynamic); (b) 2-way kt unroll with DUAL independent
// accumulator chains per wave (R12/R13 asymmetry -- serial adds hurt,
// parallel removals don't help -- fingerprints chain-latency-bound waves).
// Structure else = R13: q SoA in LDS, 1 B-frag global load per kt, NCH=8,
// kernel-boundary partials + reduce.

static constexpr int Nn = 8192;
static constexpr int Mm = 8192;
static constexpr int NCH = 8;               // m-chunks
static constexpr int NKT = 256 / NCH;       // kt per wave (32)
static constexpr float KC = 36.0673761f;    // 25 * log2(e)
static constexpr float KD = -18.0336880f;   // -12.5 * log2(e)

typedef _Float16 half8 __attribute__((ext_vector_type(8)));
typedef __fp16  fp16x2 __attribute__((ext_vector_type(2)));
typedef __fp16  fp16x4 __attribute__((ext_vector_type(4)));
typedef float  float2v __attribute__((ext_vector_type(2)));
typedef float  float4v __attribute__((ext_vector_type(4)));

#define MFMA_F16 __builtin_amdgcn_mfma_f32_16x16x32_f16
#define EXP2F(v) __builtin_amdgcn_exp2f(v)

// ---------------- prep: q SoA (constant-folded) + yf -> fp16 B-fragments
// frag idx(m,c) = (m>>5)*512 + (((m&31)>>3)*16 + c)*8 + (m&7)
__global__ __launch_bounds__(256) void mgsc_prep(
    const float* __restrict__ y, const float* __restrict__ yf,
    float* __restrict__ q, _Float16* __restrict__ frag)
{
    const int t = blockIdx.x * 256 + threadIdx.x;   // 0 .. Mm*16-1
    const int m = t >> 4, c = t & 15;
    const int idx = ((m >> 5) << 9) + ((((m & 31) >> 3) << 4) + c) * 8 + (m & 7);
    frag[idx] = (_Float16)yf[t];                    // RNE
    if (t < Mm) {
        const float ax = y[3 * t], ay = y[3 * t + 1], az = y[3 * t + 2];
        q[t]          = KC * ax;                    // qx
        q[Mm + t]     = KC * ay;                    // qy
        q[2 * Mm + t] = KC * az;                    // qz
        q[3 * Mm + t] = KD * (ax * ax + ay * ay + az * az);  // qw
    }
}

// ---------------- main: grid (128, NCH); 4 waves/block, one n-tile per wave
__global__ __launch_bounds__(256, 4) void mgsc_main(
    const float* __restrict__ x, const float* __restrict__ q,
    const _Float16* __restrict__ frag, float* __restrict__ part)
{
    __shared__ float qS[4][NKT * 32];               // 16 KB SoA: block's q chunk

    const int tid  = threadIdx.x;
    const int wave = tid >> 6, lane = tid & 63;
    const int g    = lane >> 4, c = lane & 15;
    const int xb   = blockIdx.x, yb = blockIdx.y;
    const int n0   = (xb * 4 + wave) * 16;          // this wave's n-tile
    const int nrow = n0 + c;                        // A-frag row for this lane

    // stage q chunk SoA (shared by all 4 waves: same yb); 1024 floats/comp
#pragma unroll
    for (int comp = 0; comp < 4; ++comp) {
        const float4* src = reinterpret_cast<const float4*>(q + (size_t)comp * Mm + yb * (NKT * 32));
        reinterpret_cast<float4*>(qS[comp])[tid] = src[tid];
    }

    const float xx = x[3 * nrow], xy = x[3 * nrow + 1], xz = x[3 * nrow + 2];
    const float W = KD * __fmaf_rn(xx, xx, __fmaf_rn(xy, xy, xz * xz));
    const float2v xx2 = {xx, xx}, xy2 = {xy, xy}, xz2 = {xz, xz}, W2 = {W, W};

    // dual independent accumulator chains (even/odd kt)
    float4v aE0 = {0.f, 0.f, 0.f, 0.f}, aE1 = aE0, aE2 = aE0, dE0 = aE0, dE1 = aE0, dE2 = aE0;
    float4v aO0 = aE0, aO1 = aE0, aO2 = aE0, dO0 = aE0, dO1 = aE0, dO2 = aE0;

    const _Float16 onev = (c == 0) ? (_Float16)1.0f : (_Float16)0.0f;
    half8 bone = {onev, onev, onev, onev, onev, onev, onev, onev};

    __syncthreads();                                // q chunk ready (only barrier)

    const _Float16* fbase = frag + ((size_t)yb * NKT << 9) + (lane << 3);
    half8 B0 = *reinterpret_cast<const half8*>(fbase);
    half8 B1 = *reinterpret_cast<const half8*>(fbase + 512);

    for (int ktl = 0; ktl < NKT; ktl += 2) {
        half8 Bn0, Bn1;
        if (ktl + 2 < NKT) {                        // prefetch next pair
            Bn0 = *reinterpret_cast<const half8*>(fbase + (ktl + 2) * 512);
            Bn1 = *reinterpret_cast<const half8*>(fbase + (ktl + 3) * 512);
        }
        // ---- two independent kt bodies (even -> E accs, odd -> O accs)
#pragma unroll
        for (int u = 0; u < 2; ++u) {
            const int qb = ((ktl + u) << 5) + (g << 3);
            const float4v X0 = *reinterpret_cast<const float4v*>(&qS[0][qb]);
            const float4v X1 = *reinterpret_cast<const float4v*>(&qS[0][qb + 4]);
            const float4v Y0 = *reinterpret_cast<const float4v*>(&qS[1][qb]);
            const float4v Y1 = *reinterpret_cast<const float4v*>(&qS[1][qb + 4]);
            const float4v Z0 = *reinterpret_cast<const float4v*>(&qS[2][qb]);
            const float4v Z1 = *reinterpret_cast<const float4v*>(&qS[2][qb + 4]);
            const float4v Wv0 = *reinterpret_cast<const float4v*>(&qS[3][qb]);
            const float4v Wv1 = *reinterpret_cast<const float4v*>(&qS[3][qb + 4]);

            union { fp16x2 h2[4]; half8 v; } A2, A1, A0;
#pragma unroll
            for (int p = 0; p < 4; ++p) {
                const float4v Xs = (p < 2) ? X0 : X1;
                const float4v Ys = (p < 2) ? Y0 : Y1;
                const float4v Zs = (p < 2) ? Z0 : Z1;
                const float4v Ws = (p < 2) ? Wv0 : Wv1;
                const int o = (p & 1) << 1;
                const float2v Xp = {Xs[o], Xs[o + 1]};
                const float2v Yp = {Ys[o], Ys[o + 1]};
                const float2v Zp = {Zs[o], Zs[o + 1]};
                const float2v Wp = {Ws[o], Ws[o + 1]};
                // arg pair = (W + Wp) + KC x.y  -> native v_pk_fma_f32
                float2v a = Wp + W2;                       // v_pk_add_f32
                a = __builtin_elementwise_fma(xz2, Zp, a); // v_pk_fma_f32
                a = __builtin_elementwise_fma(xy2, Yp, a);
                a = __builtin_elementwise_fma(xx2, Xp, a);
                const float e_lo = EXP2F(a.x);             // v_exp_f32 (fast, R12)
                const float e_hi = EXP2F(a.y);
                A2.h2[p] = __builtin_amdgcn_cvt_pkrtz(e_lo, e_hi);
                const fp16x2 s2 = A2.h2[p] * A2.h2[p];     // v_pk_mul_f16
                A1.h2[p] = s2 * s2;                        // e2^4  (sigma 0.1)
                const fp16x2 s1 = A1.h2[p] * A1.h2[p];
                A0.h2[p] = s1 * s1;                        // e2^16 (sigma 0.05)
            }
            const half8 B = (u == 0) ? B0 : B1;
            if (u == 0) {
                aE0 = MFMA_F16(A0.v, B, aE0, 0, 0, 0);
                aE1 = MFMA_F16(A1.v, B, aE1, 0, 0, 0);
                aE2 = MFMA_F16(A2.v, B, aE2, 0, 0, 0);
                dE0 = MFMA_F16(A0.v, bone, dE0, 0, 0, 0);
                dE1 = MFMA_F16(A1.v, bone, dE1, 0, 0, 0);
                dE2 = MFMA_F16(A2.v, bone, dE2, 0, 0, 0);
            } else {
                aO0 = MFMA_F16(A0.v, B, aO0, 0, 0, 0);
                aO1 = MFMA_F16(A1.v, B, aO1, 0, 0, 0);
                aO2 = MFMA_F16(A2.v, B, aO2, 0, 0, 0);
                dO0 = MFMA_F16(A0.v, bone, dO0, 0, 0, 0);
                dO1 = MFMA_F16(A1.v, bone, dO1, 0, 0, 0);
                dO2 = MFMA_F16(A2.v, bone, dO2, 0, 0, 0);
            }
        }
        if (ktl + 2 < NKT) { B0 = Bn0; B1 = Bn1; }
    }

    // merge dual chains
    const float4v acc0 = aE0 + aO0, acc1 = aE1 + aO1, acc2 = aE2 + aO2;
    const float4v dac0 = dE0 + dO0, dac1 = dE1 + dO1, dac2 = dE2 + dO2;

    // ---- write this wave's partial: part[yb][n][52], plain stores
    float* pb = part + ((size_t)yb * Nn) * 52;
#pragma unroll
    for (int r = 0; r < 4; ++r) {
        const int n = n0 + (g << 2) + r;            // C/D: col=c, row=g*4+r
        float* row = pb + (size_t)n * 52;
        row[c]      = acc0[r];
        row[16 + c] = acc1[r];
        row[32 + c] = acc2[r];
        if (c == 0) {
            row[48] = dac0[r];
            row[49] = dac1[r];
            row[50] = dac2[r];
        }
    }
}

// ---------------- reduce: thread (n,c) sums NCH chunks, finalizes
__global__ __launch_bounds__(256) void mgsc_reduce(
    const float* __restrict__ part, float* __restrict__ out)
{
    const int t = blockIdx.x * 256 + threadIdx.x;   // 0 .. Nn*16-1
    const int n = t >> 4, c = t & 15;
    float s0 = 0.f, s1 = 0.f, s2 = 0.f, d0 = 0.f, d1 = 0.f, d2 = 0.f;
#pragma unroll
    for (int k = 0; k < NCH; ++k) {
        const float* row = part + ((size_t)k * Nn + n) * 52;
        s0 += row[c];
        s1 += row[16 + c];
        s2 += row[32 + c];
        d0 += row[48];
        d1 += row[49];
        d2 += row[50];
    }
    out[(size_t)n * 16 + c] = 0.3f * s0 / d0 + 0.3f * s1 / d1 + 0.4f * s2 / d2;
}

// ---------------- fused VALU fallback (workspace too small)
__global__ __launch_bounds__(256) void mgsc_fused(
    const float* __restrict__ x, const float* __restrict__ y,
    const float* __restrict__ yf, float* __restrict__ out)
{
    __shared__ float yS[256 * 3];
    __shared__ float yfS[256 * 16];
    const int tid = threadIdx.x;
    const int n   = blockIdx.x * 256 + tid;
    const float xx = x[3 * n], xy = x[3 * n + 1], xz = x[3 * n + 2];
    float a0[16], a1[16], a2[16];
#pragma unroll
    for (int c = 0; c < 16; ++c) { a0[c] = 0.f; a1[c] = 0.f; a2[c] = 0.f; }
    float den0 = 0.f, den1 = 0.f, den2 = 0.f;
    for (int mt = 0; mt < Mm; mt += 256) {
        const float4* ysrc = reinterpret_cast<const float4*>(y + (size_t)mt * 3);
        if (tid < 192) reinterpret_cast<float4*>(yS)[tid] = ysrc[tid];
        const float4* fsrc = reinterpret_cast<const float4*>(yf + (size_t)mt * 16);
#pragma unroll
        for (int k = 0; k < 4; ++k)
            reinterpret_cast<float4*>(yfS)[tid + 256 * k] = fsrc[tid + 256 * k];
        __syncthreads();
        for (int mm = 0; mm < 256; ++mm) {
            const float dx = xx - yS[3 * mm], dy = xy - yS[3 * mm + 1], dz = xz - yS[3 * mm + 2];
            const float d2 = dx * dx + dy * dy + dz * dz;
            const float e2 = __expf(-12.5f * d2);
            const float t = e2 * e2, e1 = t * t, u = e1 * e1, e0 = u * u;
            den0 += e0; den1 += e1; den2 += e2;
            const float4* fr = reinterpret_cast<const float4*>(yfS + mm * 16);
#pragma unroll
            for (int k = 0; k < 4; ++k) {
                const float4 f = fr[k];
                a0[4*k+0] += e0 * f.x; a0[4*k+1] += e0 * f.y; a0[4*k+2] += e0 * f.z; a0[4*k+3] += e0 * f.w;
                a1[4*k+0] += e1 * f.x; a1[4*k+1] += e1 * f.y; a1[4*k+2] += e1 * f.z; a1[4*k+3] += e1 * f.w;
                a2[4*k+0] += e2 * f.x; a2[4*k+1] += e2 * f.y; a2[4*k+2] += e2 * f.z; a2[4*k+3] += e2 * f.w;
            }
        }
        __syncthreads();
    }
    const float r0 = 0.3f / den0, r1 = 0.3f / den1, r2 = 0.4f / den2;
#pragma unroll
    for (int c = 0; c < 16; ++c)
        out[(size_t)n * 16 + c] = a0[c] * r0 + a1[c] * r1 + a2[c] * r2;
}

extern "C" void kernel_launch(void* const* d_in, const int* in_sizes, int n_in,
                              void* d_out, int out_size, void* d_ws, size_t ws_size,
                              hipStream_t stream) {
    const float* x  = (const float*)d_in[0];
    const float* y  = (const float*)d_in[1];
    const float* yf = (const float*)d_in[2];
    float* out = (float*)d_out;

    const size_t qB    = (size_t)4 * Mm * sizeof(float);         // 128 KB SoA
    const size_t fragB = (size_t)Mm * 16 * sizeof(_Float16);     // 256 KB
    const size_t partB = (size_t)NCH * Nn * 52 * sizeof(float);  // 13.6 MB
    if (qB + fragB + partB > ws_size) {
        mgsc_fused<<<Nn / 256, 256, 0, stream>>>(x, y, yf, out);
        return;
    }
    float*    q    = (float*)d_ws;
    _Float16* frag = (_Float16*)((char*)d_ws + qB);
    float*    part = (float*)((char*)d_ws + qB + fragB);

    mgsc_prep<<<(Mm * 16) / 256, 256, 0, stream>>>(y, yf, q, frag);
    mgsc_main<<<dim3(Nn / 64, NCH), 256, 0, stream>>>(x, q, frag, part);
    mgsc_reduce<<<(Nn * 16) / 256, 256, 0, stream>>>(part, out);
}

// Round 15
// 88.565 us; speedup vs baseline: 1.0022x; 1.0022x over previous
//
#include <hip/hip_runtime.h>

// MultiGaussSpatialConv: B=1, N=M=8192, D=3, C=16, fp32.
// out[n,c] = sum_i w_i * (sum_m e_i(n,m) yf[m,c]) / (sum_m e_i(n,m))
// e_i = exp(-d2/(2 s^2)), 1/(2 s^2) = {200, 50, 12.5} -> e0 = e2^16, e1 = e2^4.
//
// R15: force REAL v_pk_fma_f32 via tied-operand asm. Reconciling R12-R14:
// +32 VALU/kt cost +15% (R12) but -40% gained 0% (R13/R14) -> the packed
// lowering never happened (R13: "=v" dest forced marshaling movs; R14:
// elementwise_fma on fp32x2 scalarizes). Fix: "+v" tied accumulate asm
// (zero-copy), asm v_pk_mul_f16 power chain, subreg-aligned pair extracts.
// Structure = R13 (best): q SoA in LDS, 1 B-frag load/kt, NCH=8,
// kernel-boundary partials + reduce.

static constexpr int Nn = 8192;
static constexpr int Mm = 8192;
static constexpr int NCH = 8;               // m-chunks
static constexpr int NKT = 256 / NCH;       // kt per wave (32)
static constexpr float KC = 36.0673761f;    // 25 * log2(e)
static constexpr float KD = -18.0336880f;   // -12.5 * log2(e)

typedef _Float16 half8 __attribute__((ext_vector_type(8)));
typedef __fp16  fp16x2 __attribute__((ext_vector_type(2)));
typedef float  float2v __attribute__((ext_vector_type(2)));
typedef float  float4v __attribute__((ext_vector_type(4)));

#define MFMA_F16 __builtin_amdgcn_mfma_f32_16x16x32_f16
#define EXP2F(v) __builtin_amdgcn_exp2f(v)

// ---------------- prep: q SoA (constant-folded) + yf -> fp16 B-fragments
// frag idx(m,c) = (m>>5)*512 + (((m&31)>>3)*16 + c)*8 + (m&7)
__global__ __launch_bounds__(256) void mgsc_prep(
    const float* __restrict__ y, const float* __restrict__ yf,
    float* __restrict__ q, _Float16* __restrict__ frag)
{
    const int t = blockIdx.x * 256 + threadIdx.x;   // 0 .. Mm*16-1
    const int m = t >> 4, c = t & 15;
    const int idx = ((m >> 5) << 9) + ((((m & 31) >> 3) << 4) + c) * 8 + (m & 7);
    frag[idx] = (_Float16)yf[t];                    // RNE
    if (t < Mm) {
        const float ax = y[3 * t], ay = y[3 * t + 1], az = y[3 * t + 2];
        q[t]          = KC * ax;                    // qx
        q[Mm + t]     = KC * ay;                    // qy
        q[2 * Mm + t] = KC * az;                    // qz
        q[3 * Mm + t] = KD * (ax * ax + ay * ay + az * az);  // qw
    }
}

// ---------------- main: grid (128, NCH); 4 waves/block, one n-tile per wave
__global__ __launch_bounds__(256, 4) void mgsc_main(
    const float* __restrict__ x, const float* __restrict__ q,
    const _Float16* __restrict__ frag, float* __restrict__ part)
{
    __shared__ float qS[4][NKT * 32];               // 16 KB SoA: block's q chunk

    const int tid  = threadIdx.x;
    const int wave = tid >> 6, lane = tid & 63;
    const int g    = lane >> 4, c = lane & 15;
    const int xb   = blockIdx.x, yb = blockIdx.y;
    const int n0   = (xb * 4 + wave) * 16;          // this wave's n-tile
    const int nrow = n0 + c;                        // A-frag row for this lane

    // stage q chunk SoA (shared by all 4 waves: same yb); 1024 floats/comp
#pragma unroll
    for (int comp = 0; comp < 4; ++comp) {
        const float4* src = reinterpret_cast<const float4*>(q + (size_t)comp * Mm + yb * (NKT * 32));
        reinterpret_cast<float4*>(qS[comp])[tid] = src[tid];
    }

    const float xx = x[3 * nrow], xy = x[3 * nrow + 1], xz = x[3 * nrow + 2];
    const float W = KD * __fmaf_rn(xx, xx, __fmaf_rn(xy, xy, xz * xz));
    const float2v xx2 = {xx, xx}, xy2 = {xy, xy}, xz2 = {xz, xz}, W2 = {W, W};

    float4v acc0 = {0.f, 0.f, 0.f, 0.f}, acc1 = acc0, acc2 = acc0;
    float4v dac0 = acc0, dac1 = acc0, dac2 = acc0;

    const _Float16 onev = (c == 0) ? (_Float16)1.0f : (_Float16)0.0f;
    half8 bone = {onev, onev, onev, onev, onev, onev, onev, onev};

    __syncthreads();                                // q chunk ready (only barrier)

    const _Float16* fpp = frag + ((size_t)yb * NKT << 9) + (lane << 3);
    half8 Bc = *reinterpret_cast<const half8*>(fpp);

    for (int ktl = 0; ktl < NKT; ++ktl) {
        half8 Bn;
        if (ktl + 1 < NKT) {                        // prefetch next B-frag
            fpp += 512;
            Bn = *reinterpret_cast<const half8*>(fpp);
        }
        const int qb = (ktl << 5) + (g << 3);
        // 8 ds_read_b128: 2 per component, conflict-free broadcast
        const float4v X0 = *reinterpret_cast<const float4v*>(&qS[0][qb]);
        const float4v X1 = *reinterpret_cast<const float4v*>(&qS[0][qb + 4]);
        const float4v Y0 = *reinterpret_cast<const float4v*>(&qS[1][qb]);
        const float4v Y1 = *reinterpret_cast<const float4v*>(&qS[1][qb + 4]);
        const float4v Z0 = *reinterpret_cast<const float4v*>(&qS[2][qb]);
        const float4v Z1 = *reinterpret_cast<const float4v*>(&qS[2][qb + 4]);
        const float4v Wv0 = *reinterpret_cast<const float4v*>(&qS[3][qb]);
        const float4v Wv1 = *reinterpret_cast<const float4v*>(&qS[3][qb + 4]);

        union { fp16x2 h2[4]; half8 v; } A2, A1, A0;
#pragma unroll
        for (int p = 0; p < 4; ++p) {
            // subregister-aligned pair extracts (elements [0,1] or [2,3])
            const float4v Xs = (p < 2) ? X0 : X1;
            const float4v Ys = (p < 2) ? Y0 : Y1;
            const float4v Zs = (p < 2) ? Z0 : Z1;
            const float4v Ws = (p < 2) ? Wv0 : Wv1;
            float2v Xp, Yp, Zp, Wp;
            if ((p & 1) == 0) {
                Xp = __builtin_shufflevector(Xs, Xs, 0, 1);
                Yp = __builtin_shufflevector(Ys, Ys, 0, 1);
                Zp = __builtin_shufflevector(Zs, Zs, 0, 1);
                Wp = __builtin_shufflevector(Ws, Ws, 0, 1);
            } else {
                Xp = __builtin_shufflevector(Xs, Xs, 2, 3);
                Yp = __builtin_shufflevector(Ys, Ys, 2, 3);
                Zp = __builtin_shufflevector(Zs, Zs, 2, 3);
                Wp = __builtin_shufflevector(Ws, Ws, 2, 3);
            }
            // arg pair = (Wp + W) + KC x.y -- tied-operand packed fp32 asm
            float2v a = Wp;
            asm("v_pk_add_f32 %0, %0, %1"        : "+v"(a) : "v"(W2));
            asm("v_pk_fma_f32 %0, %1, %2, %0"    : "+v"(a) : "v"(xz2), "v"(Zp));
            asm("v_pk_fma_f32 %0, %1, %2, %0"    : "+v"(a) : "v"(xy2), "v"(Yp));
            asm("v_pk_fma_f32 %0, %1, %2, %0"    : "+v"(a) : "v"(xx2), "v"(Xp));
            const float e_lo = EXP2F(a.x);           // v_exp_f32 (fast, R12)
            const float e_hi = EXP2F(a.y);
            A2.h2[p] = __builtin_amdgcn_cvt_pkrtz(e_lo, e_hi);
            // packed f16 power chain, asm-forced v_pk_mul_f16
            fp16x2 s2, a1, s1, a0;
            asm("v_pk_mul_f16 %0, %1, %1" : "=v"(s2) : "v"(A2.h2[p]));
            asm("v_pk_mul_f16 %0, %1, %1" : "=v"(a1) : "v"(s2));
            asm("v_pk_mul_f16 %0, %1, %1" : "=v"(s1) : "v"(a1));
            asm("v_pk_mul_f16 %0, %1, %1" : "=v"(a0) : "v"(s1));
            A1.h2[p] = a1;                           // e2^4  (sigma 0.1)
            A0.h2[p] = a0;                           // e2^16 (sigma 0.05)
        }
        acc0 = MFMA_F16(A0.v, Bc, acc0, 0, 0, 0);
        acc1 = MFMA_F16(A1.v, Bc, acc1, 0, 0, 0);
        acc2 = MFMA_F16(A2.v, Bc, acc2, 0, 0, 0);
        dac0 = MFMA_F16(A0.v, bone, dac0, 0, 0, 0);
        dac1 = MFMA_F16(A1.v, bone, dac1, 0, 0, 0);
        dac2 = MFMA_F16(A2.v, bone, dac2, 0, 0, 0);
        if (ktl + 1 < NKT) Bc = Bn;
    }

    // ---- write this wave's partial: part[yb][n][52], plain stores
    float* pb = part + ((size_t)yb * Nn) * 52;
#pragma unroll
    for (int r = 0; r < 4; ++r) {
        const int n = n0 + (g << 2) + r;            // C/D: col=c, row=g*4+r
        float* row = pb + (size_t)n * 52;
        row[c]      = acc0[r];
        row[16 + c] = acc1[r];
        row[32 + c] = acc2[r];
        if (c == 0) {
            row[48] = dac0[r];
            row[49] = dac1[r];
            row[50] = dac2[r];
        }
    }
}

// ---------------- reduce: thread (n,c) sums NCH chunks, finalizes
__global__ __launch_bounds__(256) void mgsc_reduce(
    const float* __restrict__ part, float* __restrict__ out)
{
    const int t = blockIdx.x * 256 + threadIdx.x;   // 0 .. Nn*16-1
    const int n = t >> 4, c = t & 15;
    float s0 = 0.f, s1 = 0.f, s2 = 0.f, d0 = 0.f, d1 = 0.f, d2 = 0.f;
#pragma unroll
    for (int k = 0; k < NCH; ++k) {
        const float* row = part + ((size_t)k * Nn + n) * 52;
        s0 += row[c];
        s1 += row[16 + c];
        s2 += row[32 + c];
        d0 += row[48];
        d1 += row[49];
        d2 += row[50];
    }
    out[(size_t)n * 16 + c] = 0.3f * s0 / d0 + 0.3f * s1 / d1 + 0.4f * s2 / d2;
}

// ---------------- fused VALU fallback (workspace too small)
__global__ __launch_bounds__(256) void mgsc_fused(
    const float* __restrict__ x, const float* __restrict__ y,
    const float* __restrict__ yf, float* __restrict__ out)
{
    __shared__ float yS[256 * 3];
    __shared__ float yfS[256 * 16];
    const int tid = threadIdx.x;
    const int n   = blockIdx.x * 256 + tid;
    const float xx = x[3 * n], xy = x[3 * n + 1], xz = x[3 * n + 2];
    float a0[16], a1[16], a2[16];
#pragma unroll
    for (int c = 0; c < 16; ++c) { a0[c] = 0.f; a1[c] = 0.f; a2[c] = 0.f; }
    float den0 = 0.f, den1 = 0.f, den2 = 0.f;
    for (int mt = 0; mt < Mm; mt += 256) {
        const float4* ysrc = reinterpret_cast<const float4*>(y + (size_t)mt * 3);
        if (tid < 192) reinterpret_cast<float4*>(yS)[tid] = ysrc[tid];
        const float4* fsrc = reinterpret_cast<const float4*>(yf + (size_t)mt * 16);
#pragma unroll
        for (int k = 0; k < 4; ++k)
            reinterpret_cast<float4*>(yfS)[tid + 256 * k] = fsrc[tid + 256 * k];
        __syncthreads();
        for (int mm = 0; mm < 256; ++mm) {
            const float dx = xx - yS[3 * mm], dy = xy - yS[3 * mm + 1], dz = xz - yS[3 * mm + 2];
            const float d2 = dx * dx + dy * dy + dz * dz;
            const float e2 = __expf(-12.5f * d2);
            const float t = e2 * e2, e1 = t * t, u = e1 * e1, e0 = u * u;
            den0 += e0; den1 += e1; den2 += e2;
            const float4* fr = reinterpret_cast<const float4*>(yfS + mm * 16);
#pragma unroll
            for (int k = 0; k < 4; ++k) {
                const float4 f = fr[k];
                a0[4*k+0] += e0 * f.x; a0[4*k+1] += e0 * f.y; a0[4*k+2] += e0 * f.z; a0[4*k+3] += e0 * f.w;
                a1[4*k+0] += e1 * f.x; a1[4*k+1] += e1 * f.y; a1[4*k+2] += e1 * f.z; a1[4*k+3] += e1 * f.w;
                a2[4*k+0] += e2 * f.x; a2[4*k+1] += e2 * f.y; a2[4*k+2] += e2 * f.z; a2[4*k+3] += e2 * f.w;
            }
        }
        __syncthreads();
    }
    const float r0 = 0.3f / den0, r1 = 0.3f / den1, r2 = 0.4f / den2;
#pragma unroll
    for (int c = 0; c < 16; ++c)
        out[(size_t)n * 16 + c] = a0[c] * r0 + a1[c] * r1 + a2[c] * r2;
}

extern "C" void kernel_launch(void* const* d_in, const int* in_sizes, int n_in,
                              void* d_out, int out_size, void* d_ws, size_t ws_size,
                              hipStream_t stream) {
    const float* x  = (const float*)d_in[0];
    const float* y  = (const float*)d_in[1];
    const float* yf = (const float*)d_in[2];
    float* out = (float*)d_out;

    const size_t qB    = (size_t)4 * Mm * sizeof(float);         // 128 KB SoA
    const size_t fragB = (size_t)Mm * 16 * sizeof(_Float16);     // 256 KB
    const size_t partB = (size_t)NCH * Nn * 52 * sizeof(float);  // 13.6 MB
    if (qB + fragB + partB > ws_size) {
        mgsc_fused<<<Nn / 256, 256, 0, stream>>>(x, y, yf, out);
        return;
    }
    float*    q    = (float*)d_ws;
    _Float16* frag = (_Float16*)((char*)d_ws + qB);
    float*    part = (float*)((char*)d_ws + qB + fragB);

    mgsc_prep<<<(Mm * 16) / 256, 256, 0, stream>>>(y, yf, q, frag);
    mgsc_main<<<dim3(Nn / 64, NCH), 256, 0, stream>>>(x, q, frag, part);
    mgsc_reduce<<<(Nn * 16) / 256, 256, 0, stream>>>(part, out);
}